// Round 1
// baseline (1717.014 us; speedup 1.0000x reference)
//
#include <hip/hip_runtime.h>

#define LEN_C 512
#define R_DIM 4
#define S_DIM 8
#define E_DIM 8
#define T_DIM 2048
#define Q_DIM (R_DIM * S_DIM)            // 32
#define W_ELEMS (Q_DIM * LEN_C)          // 16384
#define PER_T (Q_DIM * E_DIM * LEN_C)    // 131072 floats per t
#define LR_CONST 0.001f

// ---------------------------------------------------------------------------
// Kernel 1: partial[q][e] = sum_n Fx[q,e,n] * W0[q,n]
// One block per q (32 blocks), 256 threads (4 waves).
// Wave w computes e = {2w, 2w+1}; each lane covers the n-row via 2 float4s.
// ---------------------------------------------------------------------------
__global__ __launch_bounds__(256) void grad_kernel(
    const float* __restrict__ Fx, const float* __restrict__ W0,
    float* __restrict__ partial) {
  const int q = blockIdx.x;
  const int lane = threadIdx.x & 63;
  const int wave = threadIdx.x >> 6;

  const float4* c = (const float4*)(W0 + (size_t)q * LEN_C);
  const float4 w0 = c[lane];
  const float4 w1 = c[lane + 64];
  const float4* fb = (const float4*)(Fx + (size_t)q * (E_DIM * LEN_C));

  float acc[2];
#pragma unroll
  for (int j = 0; j < 2; ++j) {
    const int e = wave * 2 + j;
    const float4 fa = fb[e * 128 + lane];
    const float4 fc = fb[e * 128 + lane + 64];
    acc[j] = fa.x * w0.x + fa.y * w0.y + fa.z * w0.z + fa.w * w0.w +
             fc.x * w1.x + fc.y * w1.y + fc.z * w1.z + fc.w * w1.w;
  }

#pragma unroll
  for (int j = 0; j < 2; ++j) {
    float v = acc[j];
    for (int off = 32; off; off >>= 1) v += __shfl_down(v, off, 64);
    if (lane == 0) partial[q * E_DIM + wave * 2 + j] = v;
  }
}

// ---------------------------------------------------------------------------
// Kernel 2: err[e] = Dis[e, LEN_C-1] - sum_q partial[q][e]   (tiny preamble)
//           cw[q,n] = W0[q,n] + LR * sum_e err[e] * Fx[q,e,n]
// 64 blocks x 256 threads (16384 elements). Fx is L2-hot from kernel 1.
// ---------------------------------------------------------------------------
__global__ __launch_bounds__(256) void cw_kernel(
    const float* __restrict__ Fx, const float* __restrict__ Dis,
    const float* __restrict__ partial, const float* __restrict__ W0,
    float* __restrict__ cw) {
  __shared__ float serr[E_DIM];
  if (threadIdx.x < E_DIM) {
    float s = 0.0f;
#pragma unroll
    for (int qq = 0; qq < Q_DIM; ++qq) s += partial[qq * E_DIM + threadIdx.x];
    serr[threadIdx.x] = Dis[threadIdx.x * LEN_C + (LEN_C - 1)] - s;
  }
  __syncthreads();

  const int idx = blockIdx.x * 256 + threadIdx.x;
  const int q = idx >> 9;          // / LEN_C
  const int n = idx & (LEN_C - 1);
  const float* f = Fx + ((size_t)q * E_DIM) * LEN_C + n;
  float s = 0.0f;
#pragma unroll
  for (int e = 0; e < E_DIM; ++e) s += serr[e] * f[e * LEN_C];
  cw[idx] = W0[idx] + LR_CONST * s;
}

// ---------------------------------------------------------------------------
// Kernel 3: anti_noise[t,e] = sum_{q,n} Fx_extend[t,q,e,n] * cw[q,n]
// One block per t (2048 blocks), 256 threads = 4 waves. Wave w owns
// q = w + 4*i. cw fragments are re-loaded per i from L2 (64 KB, resident on
// every XCD) instead of hoisting 64 VGPRs; __launch_bounds__(256,4) caps
// VGPRs at 128 -> 4 blocks/CU = 16 waves/CU for the HBM stream.
// ---------------------------------------------------------------------------
__global__ __launch_bounds__(256, 4) void adapt_kernel(
    const float* __restrict__ fxe, const float* __restrict__ cw,
    float* __restrict__ out) {
  const int t = blockIdx.x;
  const int lane = threadIdx.x & 63;
  const int wave = threadIdx.x >> 6;
  const float4* __restrict__ base =
      (const float4*)(fxe + (size_t)t * PER_T) + (size_t)wave * (E_DIM * 128);

  float acc[E_DIM];
#pragma unroll
  for (int e = 0; e < E_DIM; ++e) acc[e] = 0.0f;

#pragma unroll
  for (int i = 0; i < 8; ++i) {
    const int q = wave + 4 * i;
    const float4* c = (const float4*)(cw + (size_t)q * LEN_C);
    const float4 w0 = c[lane];
    const float4 w1 = c[lane + 64];
    const float4* fb = base + (size_t)i * (4 * E_DIM * 128);
#pragma unroll
    for (int e = 0; e < E_DIM; ++e) {
      const float4 fa = fb[e * 128 + lane];
      const float4 fc = fb[e * 128 + lane + 64];
      acc[e] += fa.x * w0.x + fa.y * w0.y + fa.z * w0.z + fa.w * w0.w +
                fc.x * w1.x + fc.y * w1.y + fc.z * w1.z + fc.w * w1.w;
    }
  }

  __shared__ float lds[4 * 8];
#pragma unroll
  for (int e = 0; e < E_DIM; ++e) {
    float v = acc[e];
    for (int off = 32; off; off >>= 1) v += __shfl_down(v, off, 64);
    if (lane == 0) lds[wave * 8 + e] = v;
  }
  __syncthreads();
  if (threadIdx.x < E_DIM) {
    out[(size_t)t * E_DIM + threadIdx.x] =
        lds[threadIdx.x] + lds[8 + threadIdx.x] + lds[16 + threadIdx.x] +
        lds[24 + threadIdx.x];
  }
}

// ---------------------------------------------------------------------------
// Kernel 4: gam_vector[i] = 0.99^(LEN_C-1-i)
// ---------------------------------------------------------------------------
__global__ void gam_kernel(float* __restrict__ out) {
  const int i = threadIdx.x;
  out[T_DIM * E_DIM + i] = powf(0.99f, (float)(LEN_C - 1 - i));
}

extern "C" void kernel_launch(void* const* d_in, const int* in_sizes, int n_in,
                              void* d_out, int out_size, void* d_ws,
                              size_t ws_size, hipStream_t stream) {
  const float* Fx = (const float*)d_in[0];         // [4,8,8,512]
  const float* Dis = (const float*)d_in[1];        // [8,512]
  const float* Fxe = (const float*)d_in[2];        // [2048,4,8,8,512]
  const float* W0 = (const float*)d_in[3];         // [4,8,512]
  float* out = (float*)d_out;                      // 16384 + 512

  float* partial = (float*)d_ws;                   // 256 floats [q][e]
  float* cw = (float*)((char*)d_ws + 1024);        // 16384 floats, 16B aligned

  grad_kernel<<<Q_DIM, 256, 0, stream>>>(Fx, W0, partial);
  cw_kernel<<<W_ELEMS / 256, 256, 0, stream>>>(Fx, Dis, partial, W0, cw);
  adapt_kernel<<<T_DIM, 256, 0, stream>>>(Fxe, cw, out);
  gam_kernel<<<1, LEN_C, 0, stream>>>(out);
}